// Round 1
// baseline (350.518 us; speedup 1.0000x reference)
//
#include <hip/hip_runtime.h>
#include <stdint.h>

typedef unsigned short ushort_t;
typedef unsigned int uint32;

typedef __attribute__((ext_vector_type(8))) short short8;
typedef __attribute__((ext_vector_type(4))) float floatx4;

#define NEG_SLOPE 0.2f

__device__ __forceinline__ ushort_t f2bf(float f) {
    union { float f; uint32 u; } v; v.f = f;
    uint32 u = v.u;
    uint32 r = (u + 0x7fffu + ((u >> 16) & 1u)) >> 16;
    return (ushort_t)r;
}
__device__ __forceinline__ float2 bf2x(uint32 u) {
    union { uint32 u; float f; } a, b;
    a.u = u << 16; b.u = u & 0xffff0000u;
    float2 r; r.x = a.f; r.y = b.f; return r;
}

// ---------------- dtype sniffer ----------------
__global__ void k_sniff(const uint32* __restrict__ x, int* __restrict__ flag) {
    __shared__ int sh[256];
    int t = threadIdx.x;
    int c = 0;
    for (int i = t; i < 1024; i += 256) {
        uint32 h = x[i] & 0xFFFFu;
        uint32 e = (h >> 7) & 0xFFu;
        if (h == 0u || (e >= 100u && e <= 140u)) c++;
    }
    sh[t] = c; __syncthreads();
    for (int off = 128; off >= 1; off >>= 1) {
        if (t < off) sh[t] += sh[t + off];
        __syncthreads();
    }
    if (t == 0) flag[0] = (sh[0] >= 512) ? 1 : 0;
}

// ---------------- GEMM body (shared by fused layer-0 kernel and k_gemm) ----------------
__device__ __forceinline__ void gemm_body(int bid, int tid,
                                          const void* __restrict__ actv,
                                          const ushort_t* __restrict__ W,
                                          ushort_t* __restrict__ hb,
                                          float* __restrict__ als,
                                          float* __restrict__ ald,
                                          const ushort_t* __restrict__ asrcp,
                                          const ushort_t* __restrict__ adstp,
                                          int N, int layer0,
                                          const int* __restrict__ flag) {
    int wid = tid >> 6, lane = tid & 63;
    int n0 = (bid * 4 + wid) * 16;
    int mrow = lane & 15, quad = lane >> 4;
    int n = n0 + mrow;
    bool isf32 = (layer0 && !flag[0]);
    short8 a[4];
    if (n < N) {
        if (isf32) {
            const float* ar = (const float*)actv + (size_t)n * 128 + quad * 8;
            #pragma unroll
            for (int kt = 0; kt < 4; kt++) {
                float4 fa = *(const float4*)(ar + kt * 32);
                float4 fb = *(const float4*)(ar + kt * 32 + 4);
                short8 v;
                v[0] = (short)f2bf(fa.x); v[1] = (short)f2bf(fa.y);
                v[2] = (short)f2bf(fa.z); v[3] = (short)f2bf(fa.w);
                v[4] = (short)f2bf(fb.x); v[5] = (short)f2bf(fb.y);
                v[6] = (short)f2bf(fb.z); v[7] = (short)f2bf(fb.w);
                a[kt] = v;
            }
        } else {
            const ushort_t* ar = (const ushort_t*)actv + (size_t)n * 128 + quad * 8;
            #pragma unroll
            for (int kt = 0; kt < 4; kt++) a[kt] = *(const short8*)(ar + kt * 32);
        }
    } else {
        #pragma unroll
        for (int kt = 0; kt < 4; kt++) { short8 z = {0,0,0,0,0,0,0,0}; a[kt] = z; }
    }
    float ps[4], pd[4];
    #pragma unroll
    for (int t = 0; t < 8; t++) {
        if ((t & 1) == 0) {
            #pragma unroll
            for (int r = 0; r < 4; r++) { ps[r] = 0.f; pd[r] = 0.f; }
        }
        const ushort_t* wr = W + (size_t)(t * 16 + mrow) * 128 + quad * 8;
        floatx4 acc = {0.f, 0.f, 0.f, 0.f};
        #pragma unroll
        for (int kt = 0; kt < 4; kt++) {
            short8 b = *(const short8*)(wr + kt * 32);
            acc = __builtin_amdgcn_mfma_f32_16x16x32_bf16(a[kt], b, acc, 0, 0, 0);
        }
        int col = t * 16 + mrow;
        union { uint32 u; float f; } cs, cd;
        cs.u = ((uint32)asrcp[col]) << 16;
        cd.u = ((uint32)adstp[col]) << 16;
        #pragma unroll
        for (int r = 0; r < 4; r++) {
            int rn = n0 + quad * 4 + r;
            if (rn < N) hb[(size_t)rn * 128 + col] = f2bf(acc[r]);
            ps[r] += acc[r] * cs.f;
            pd[r] += acc[r] * cd.f;
        }
        if (t & 1) {
            #pragma unroll
            for (int off = 1; off <= 8; off <<= 1) {
                #pragma unroll
                for (int r = 0; r < 4; r++) {
                    ps[r] += __shfl_xor(ps[r], off);
                    pd[r] += __shfl_xor(pd[r], off);
                }
            }
            int h = t >> 1;
            if (mrow < 8) {
                int r = mrow & 3;
                float vs = r == 0 ? ps[0] : r == 1 ? ps[1] : r == 2 ? ps[2] : ps[3];
                float vd = r == 0 ? pd[0] : r == 1 ? pd[1] : r == 2 ? pd[2] : pd[3];
                int rn = n0 + quad * 4 + r;
                if (rn < N) {
                    float* dp = (mrow < 4) ? als : ald;
                    dp[(size_t)rn * 4 + h] = (mrow < 4) ? vs : vd;
                }
            }
        }
    }
}

__global__ __launch_bounds__(256) void k_gemm(const void* __restrict__ actv,
                                              const ushort_t* __restrict__ W,
                                              ushort_t* __restrict__ hb,
                                              float* __restrict__ als,
                                              float* __restrict__ ald,
                                              const ushort_t* __restrict__ asrcp,
                                              const ushort_t* __restrict__ adstp,
                                              int N, const int* __restrict__ flag) {
    gemm_body(blockIdx.x, threadIdx.x, actv, W, hb, als, ald, asrcp, adstp, N, 0, flag);
}

// ---------------- fused: param canonicalization (197 blocks) | hist x4-unrolled (rest) ----------------
__global__ void k_f1(const void* W0, const void* W1, const void* W2,
                     const void* s0, const void* s1, const void* s2,
                     const void* a0, const void* a1, const void* a2,
                     const void* b0, const void* b1, const void* b2,
                     ushort_t* __restrict__ pblk, const int* __restrict__ flag,
                     const int* __restrict__ dst, int* __restrict__ cnt,
                     int* __restrict__ rank, int E) {
    if (blockIdx.x < 197) {
        int i = blockIdx.x * 256 + threadIdx.x;
        if (i >= 50304) return;
        const void* src; int off;
        if (i < 49152) {
            int seg = i / 16384; off = i % 16384;
            src = seg == 0 ? W0 : seg == 1 ? W1 : W2;
        } else if (i < 49536) {
            int j = i - 49152; int seg = j / 128; off = j % 128;
            src = seg == 0 ? s0 : seg == 1 ? s1 : s2;
        } else if (i < 49920) {
            int j = i - 49536; int seg = j / 128; off = j % 128;
            src = seg == 0 ? a0 : seg == 1 ? a1 : a2;
        } else {
            int j = i - 49920; int seg = j / 128; off = j % 128;
            src = seg == 0 ? b0 : seg == 1 ? b1 : b2;
        }
        if (flag[0]) pblk[i] = ((const ushort_t*)src)[off];
        else         pblk[i] = f2bf(((const float*)src)[off]);
    } else {
        // 4 edges per thread: independent atomic chains overlap latency
        int e0 = ((blockIdx.x - 197) * 256 + threadIdx.x) * 4;
        if (e0 + 3 < E) {
            int4 d4 = *(const int4*)(dst + e0);
            int r0 = atomicAdd(&cnt[d4.x], 1);
            int r1 = atomicAdd(&cnt[d4.y], 1);
            int r2 = atomicAdd(&cnt[d4.z], 1);
            int r3 = atomicAdd(&cnt[d4.w], 1);
            int4 r4 = {r0, r1, r2, r3};
            *(int4*)(rank + e0) = r4;
        } else {
            for (int e = e0; e < E; e++) rank[e] = atomicAdd(&cnt[dst[e]], 1);
        }
    }
}

// ---------------- fused: scan_a (nb blocks) | gemm layer-0 (rest) ----------------
__global__ __launch_bounds__(256) void k_f2(const int* __restrict__ cnt, int* __restrict__ ro,
                                            int* __restrict__ bsum, int n, int nb,
                                            const void* __restrict__ actv,
                                            const ushort_t* __restrict__ W,
                                            ushort_t* __restrict__ hb,
                                            float* __restrict__ als, float* __restrict__ ald,
                                            const ushort_t* __restrict__ asrcp,
                                            const ushort_t* __restrict__ adstp,
                                            int N, const int* __restrict__ flag) {
    if ((int)blockIdx.x < nb) {
        __shared__ int sd[256];
        int t = threadIdx.x;
        int base = blockIdx.x * 1024 + t * 4;
        int v0 = (base + 0 < n) ? cnt[base + 0] : 0;
        int v1 = (base + 1 < n) ? cnt[base + 1] : 0;
        int v2 = (base + 2 < n) ? cnt[base + 2] : 0;
        int v3 = (base + 3 < n) ? cnt[base + 3] : 0;
        int s = v0 + v1 + v2 + v3;
        sd[t] = s; __syncthreads();
        for (int off = 1; off < 256; off <<= 1) {
            int x = 0;
            if (t >= off) x = sd[t - off];
            __syncthreads();
            sd[t] += x;
            __syncthreads();
        }
        int run = sd[t] - s;
        run += v0; if (base + 0 < n) ro[base + 1] = run;
        run += v1; if (base + 1 < n) ro[base + 2] = run;
        run += v2; if (base + 2 < n) ro[base + 3] = run;
        run += v3; if (base + 3 < n) ro[base + 4] = run;
        if (t == 255) bsum[blockIdx.x] = sd[255];
    } else {
        gemm_body(blockIdx.x - nb, threadIdx.x, actv, W, hb, als, ald, asrcp, adstp, N, 1, flag);
    }
}

__global__ void k_scan_bc(int* __restrict__ ro, const int* __restrict__ bsum,
                          int n, int nb) {
    __shared__ int pre[256];
    int t = threadIdx.x;
    if (t == 0) {
        int acc = 0;
        for (int b = 0; b < nb; b++) { pre[b] = acc; acc += bsum[b]; }
    }
    __syncthreads();
    int i = blockIdx.x * 256 + t;
    if (i == 0) ro[0] = 0;
    if (i < n) ro[i + 1] += pre[i >> 10];
}

// atomic-free scatter; u16 node indices (requires N < 65536); x4 unrolled
__global__ void k_scatter(const int* __restrict__ src, const int* __restrict__ dst,
                          const int* __restrict__ ro, const int* __restrict__ rank,
                          ushort_t* __restrict__ ssrc, int E) {
    int e0 = (blockIdx.x * 256 + threadIdx.x) * 4;
    if (e0 + 3 < E) {
        int4 d4 = *(const int4*)(dst + e0);
        int4 s4 = *(const int4*)(src + e0);
        int4 r4 = *(const int4*)(rank + e0);
        ssrc[ro[d4.x] + r4.x] = (ushort_t)s4.x;
        ssrc[ro[d4.y] + r4.y] = (ushort_t)s4.y;
        ssrc[ro[d4.z] + r4.z] = (ushort_t)s4.z;
        ssrc[ro[d4.w] + r4.w] = (ushort_t)s4.w;
    } else {
        for (int e = e0; e < E; e++) ssrc[ro[dst[e]] + rank[e]] = (ushort_t)src[e];
    }
}

// ---------------- softmax + aggregation: 1 wave / node, single pass (no max-sub) ----------------
// Softmax is shift-invariant; scores here are bounded (|t| <~ 8), so exp(t) is fp32-safe.
// Accumulate phase: 4 edges/iteration; lane = grp(edge-in-quad, lane>>4) x sub(channel
// block, lane&15). Each lane loads 16B (8 bf16 channels) per iteration -> dwordx4,
// 4x fewer VMEM instructions and 4x shorter j-loop than the 4B/lane variant.
__global__ __launch_bounds__(64) void k_agg(const int* __restrict__ ro,
                                            const ushort_t* __restrict__ ssrc,
                                            const ushort_t* __restrict__ hb,
                                            const float* __restrict__ als,
                                            const float* __restrict__ ald_,
                                            const ushort_t* __restrict__ bias,
                                            void* __restrict__ outp, int N, int apply_elu,
                                            int is_final, const int* __restrict__ flag) {
    int n = blockIdx.x;
    int lane = threadIdx.x;
    int r0 = ro[n], r1 = ro[n + 1];
    floatx4 ad = *(const floatx4*)(ald_ + (size_t)n * 4);
    const char* alsb = (const char*)als;

    __shared__ __align__(16) float wsm[256];
    __shared__ int osm[64];

    int grp = lane >> 4;      // which edge within a quad of edges
    int sub = lane & 15;      // channel block: owns channels [sub*8, sub*8+8)
    int hd = sub >> 2;        // head of owned channels (8 channels never cross a head)

    float acc[8];
    #pragma unroll
    for (int k = 0; k < 8; k++) acc[k] = 0.f;
    float d0 = 0.f, d1 = 0.f, d2 = 0.f, d3 = 0.f;

    for (int base = r0; base < r1; base += 64) {
        int i = base + lane;
        if (i < r1) {
            int s = ssrc[i];
            floatx4 as = *(const floatx4*)(alsb + (s << 4));
            // leakyrelu(t) = max(t, 0.2t); w = exp(.) unshifted
            float t0 = as.x + ad.x; float w0 = __expf(fmaxf(t0, NEG_SLOPE * t0)); d0 += w0;
            float t1 = as.y + ad.y; float w1 = __expf(fmaxf(t1, NEG_SLOPE * t1)); d1 += w1;
            float t2 = as.z + ad.z; float w2 = __expf(fmaxf(t2, NEG_SLOPE * t2)); d2 += w2;
            float t3 = as.w + ad.w; float w3 = __expf(fmaxf(t3, NEG_SLOPE * t3)); d3 += w3;
            osm[lane] = s << 8;            // row byte offset
            floatx4 w4 = {w0, w1, w2, w3};
            *(floatx4*)(wsm + lane * 4) = w4;
        }
        __builtin_amdgcn_wave_barrier();
        int cend = min(64, r1 - base);
        #pragma unroll 4
        for (int j = 0; j < cend; j += 4) {
            int je = j + grp;
            if (je < cend) {
                float wj = wsm[je * 4 + hd];
                const char* rp = (const char*)hb + (uint32)osm[je] + (sub << 4);
                short8 hv = *(const short8*)rp;   // 8 bf16 channels, dwordx4
                #pragma unroll
                for (int k = 0; k < 8; k++) {
                    union { uint32 u; float f; } c;
                    c.u = ((uint32)(ushort_t)hv[k]) << 16;
                    acc[k] += wj * c.f;
                }
            }
        }
        __builtin_amdgcn_wave_barrier();
    }
    // fold the 4 edge-groups: lanes {sub, sub+16, sub+32, sub+48} hold the same channels
    #pragma unroll
    for (int k = 0; k < 8; k++) {
        acc[k] += __shfl_xor(acc[k], 16);
        acc[k] += __shfl_xor(acc[k], 32);
    }
    // denominators: full-wave reduce (each lane contributed its own edges)
    #pragma unroll
    for (int off = 32; off >= 1; off >>= 1) {
        d0 += __shfl_xor(d0, off); d1 += __shfl_xor(d1, off);
        d2 += __shfl_xor(d2, off); d3 += __shfl_xor(d3, off);
    }
    if (grp == 0) {
        float den = (hd == 0 ? d0 : hd == 1 ? d1 : hd == 2 ? d2 : d3) + 1e-16f;
        float inv = 1.0f / den;
        int c0 = sub << 3;
        short8 bv8 = *(const short8*)(bias + c0);
        float o[8];
        #pragma unroll
        for (int k = 0; k < 8; k++) {
            union { uint32 u; float f; } b;
            b.u = ((uint32)(ushort_t)bv8[k]) << 16;
            o[k] = acc[k] * inv + b.f;
            if (apply_elu) o[k] = o[k] > 0.f ? o[k] : expm1f(o[k]);
        }
        if (is_final && !flag[0]) {
            float* op = (float*)outp + (size_t)n * 128 + c0;
            float4 lo = {o[0], o[1], o[2], o[3]};
            float4 hi = {o[4], o[5], o[6], o[7]};
            *(float4*)op = lo;
            *(float4*)(op + 4) = hi;
        } else {
            short8 pk;
            #pragma unroll
            for (int k = 0; k < 8; k++) pk[k] = (short)f2bf(o[k]);
            *(short8*)((ushort_t*)outp + (size_t)n * 128 + c0) = pk;
        }
    }
}

extern "C" void kernel_launch(void* const* d_in, const int* in_sizes, int n_in,
                              void* d_out, int out_size, void* d_ws, size_t ws_size,
                              hipStream_t stream) {
    const void* x = d_in[0];
    const int* src = (const int*)d_in[1];
    const int* dst = (const int*)d_in[2];
    const int N = in_sizes[0] / 128;   // 50000 (< 65536 required for u16 ssrc)
    const int E = in_sizes[1];

    char* p = (char*)d_ws;
    auto alloc = [&](size_t bytes) { char* r = p; p += (bytes + 255) & ~(size_t)255; return r; };
    int*      flag  = (int*)alloc(256);
    int*      bsum  = (int*)alloc(256 * 4);
    int*      ro    = (int*)alloc((size_t)(N + 1) * 4);
    ushort_t* ssrc  = (ushort_t*)alloc((size_t)E * 2);         // also aliases cnt (int[N]) early
    ushort_t* hb    = (ushort_t*)alloc((size_t)N * 128 * 2);
    float*    als   = (float*)alloc((size_t)N * 4 * 4);
    float*    ald   = (float*)alloc((size_t)N * 4 * 4);
    ushort_t* xact  = (ushort_t*)alloc((size_t)N * 128 * 2);   // also aliases rank (int[E]) early
    ushort_t* pblk  = (ushort_t*)alloc((size_t)50304 * 2);

    int* cnt  = (int*)ssrc;    // dead once scatter overwrites ssrc
    int* rank = (int*)xact;    // dead once agg0 writes xact

    int g256e4 = (E + 1023) / 1024;
    int g256n = (N + 255) / 256;
    int nb = (N + 1023) / 1024;
    int gg = (N + 63) / 64;

    k_sniff<<<1, 256, 0, stream>>>((const uint32*)x, flag);
    hipMemsetAsync(cnt, 0, (size_t)N * 4, stream);
    k_f1<<<197 + g256e4, 256, 0, stream>>>(
        d_in[3], d_in[7], d_in[11],
        d_in[4], d_in[8], d_in[12],
        d_in[5], d_in[9], d_in[13],
        d_in[6], d_in[10], d_in[14],
        pblk, flag, dst, cnt, rank, E);
    k_f2<<<nb + gg, 256, 0, stream>>>(cnt, ro, bsum, N, nb,
        x, pblk, hb, als, ald, pblk + 49152, pblk + 49536, N, flag);
    k_scan_bc<<<g256n, 256, 0, stream>>>(ro, bsum, N, nb);
    k_scatter<<<g256e4, 256, 0, stream>>>(src, dst, ro, rank, ssrc, E);

    for (int l = 0; l < 3; l++) {
        const ushort_t* As = pblk + 49152 + l * 128;
        const ushort_t* Ad = pblk + 49536 + l * 128;
        const ushort_t* Bc = pblk + 49920 + l * 128;
        void* outp = (l == 2) ? d_out : (void*)xact;
        if (l > 0) {
            const ushort_t* Wc = pblk + (size_t)l * 16384;
            k_gemm<<<gg, 256, 0, stream>>>(xact, Wc, hb, als, ald, As, Ad, N, flag);
        }
        k_agg<<<N, 64, 0, stream>>>(ro, ssrc, hb, als, ald, Bc, outp, N, l < 2 ? 1 : 0,
                                    l == 2 ? 1 : 0, flag);
    }
}

// Round 2
// 345.417 us; speedup vs baseline: 1.0148x; 1.0148x over previous
//
#include <hip/hip_runtime.h>
#include <stdint.h>

typedef unsigned short ushort_t;
typedef unsigned int uint32;

typedef __attribute__((ext_vector_type(8))) short short8;
typedef __attribute__((ext_vector_type(4))) float floatx4;

#define NEG_SLOPE 0.2f

__device__ __forceinline__ ushort_t f2bf(float f) {
    union { float f; uint32 u; } v; v.f = f;
    uint32 u = v.u;
    uint32 r = (u + 0x7fffu + ((u >> 16) & 1u)) >> 16;
    return (ushort_t)r;
}
__device__ __forceinline__ float2 bf2x(uint32 u) {
    union { uint32 u; float f; } a, b;
    a.u = u << 16; b.u = u & 0xffff0000u;
    float2 r; r.x = a.f; r.y = b.f; return r;
}

// ---------------- dtype sniffer ----------------
__global__ void k_sniff(const uint32* __restrict__ x, int* __restrict__ flag) {
    __shared__ int sh[256];
    int t = threadIdx.x;
    int c = 0;
    for (int i = t; i < 1024; i += 256) {
        uint32 h = x[i] & 0xFFFFu;
        uint32 e = (h >> 7) & 0xFFu;
        if (h == 0u || (e >= 100u && e <= 140u)) c++;
    }
    sh[t] = c; __syncthreads();
    for (int off = 128; off >= 1; off >>= 1) {
        if (t < off) sh[t] += sh[t + off];
        __syncthreads();
    }
    if (t == 0) flag[0] = (sh[0] >= 512) ? 1 : 0;
}

// ---------------- GEMM body (shared by fused layer-0 kernel and k_gemm) ----------------
__device__ __forceinline__ void gemm_body(int bid, int tid,
                                          const void* __restrict__ actv,
                                          const ushort_t* __restrict__ W,
                                          ushort_t* __restrict__ hb,
                                          float* __restrict__ als,
                                          float* __restrict__ ald,
                                          const ushort_t* __restrict__ asrcp,
                                          const ushort_t* __restrict__ adstp,
                                          int N, int layer0,
                                          const int* __restrict__ flag) {
    int wid = tid >> 6, lane = tid & 63;
    int n0 = (bid * 4 + wid) * 16;
    int mrow = lane & 15, quad = lane >> 4;
    int n = n0 + mrow;
    bool isf32 = (layer0 && !flag[0]);
    short8 a[4];
    if (n < N) {
        if (isf32) {
            const float* ar = (const float*)actv + (size_t)n * 128 + quad * 8;
            #pragma unroll
            for (int kt = 0; kt < 4; kt++) {
                float4 fa = *(const float4*)(ar + kt * 32);
                float4 fb = *(const float4*)(ar + kt * 32 + 4);
                short8 v;
                v[0] = (short)f2bf(fa.x); v[1] = (short)f2bf(fa.y);
                v[2] = (short)f2bf(fa.z); v[3] = (short)f2bf(fa.w);
                v[4] = (short)f2bf(fb.x); v[5] = (short)f2bf(fb.y);
                v[6] = (short)f2bf(fb.z); v[7] = (short)f2bf(fb.w);
                a[kt] = v;
            }
        } else {
            const ushort_t* ar = (const ushort_t*)actv + (size_t)n * 128 + quad * 8;
            #pragma unroll
            for (int kt = 0; kt < 4; kt++) a[kt] = *(const short8*)(ar + kt * 32);
        }
    } else {
        #pragma unroll
        for (int kt = 0; kt < 4; kt++) { short8 z = {0,0,0,0,0,0,0,0}; a[kt] = z; }
    }
    float ps[4], pd[4];
    #pragma unroll
    for (int t = 0; t < 8; t++) {
        if ((t & 1) == 0) {
            #pragma unroll
            for (int r = 0; r < 4; r++) { ps[r] = 0.f; pd[r] = 0.f; }
        }
        const ushort_t* wr = W + (size_t)(t * 16 + mrow) * 128 + quad * 8;
        floatx4 acc = {0.f, 0.f, 0.f, 0.f};
        #pragma unroll
        for (int kt = 0; kt < 4; kt++) {
            short8 b = *(const short8*)(wr + kt * 32);
            acc = __builtin_amdgcn_mfma_f32_16x16x32_bf16(a[kt], b, acc, 0, 0, 0);
        }
        int col = t * 16 + mrow;
        union { uint32 u; float f; } cs, cd;
        cs.u = ((uint32)asrcp[col]) << 16;
        cd.u = ((uint32)adstp[col]) << 16;
        #pragma unroll
        for (int r = 0; r < 4; r++) {
            int rn = n0 + quad * 4 + r;
            if (rn < N) hb[(size_t)rn * 128 + col] = f2bf(acc[r]);
            ps[r] += acc[r] * cs.f;
            pd[r] += acc[r] * cd.f;
        }
        if (t & 1) {
            #pragma unroll
            for (int off = 1; off <= 8; off <<= 1) {
                #pragma unroll
                for (int r = 0; r < 4; r++) {
                    ps[r] += __shfl_xor(ps[r], off);
                    pd[r] += __shfl_xor(pd[r], off);
                }
            }
            int h = t >> 1;
            if (mrow < 8) {
                int r = mrow & 3;
                float vs = r == 0 ? ps[0] : r == 1 ? ps[1] : r == 2 ? ps[2] : ps[3];
                float vd = r == 0 ? pd[0] : r == 1 ? pd[1] : r == 2 ? pd[2] : pd[3];
                int rn = n0 + quad * 4 + r;
                if (rn < N) {
                    float* dp = (mrow < 4) ? als : ald;
                    dp[(size_t)rn * 4 + h] = (mrow < 4) ? vs : vd;
                }
            }
        }
    }
}

__global__ __launch_bounds__(256) void k_gemm(const void* __restrict__ actv,
                                              const ushort_t* __restrict__ W,
                                              ushort_t* __restrict__ hb,
                                              float* __restrict__ als,
                                              float* __restrict__ ald,
                                              const ushort_t* __restrict__ asrcp,
                                              const ushort_t* __restrict__ adstp,
                                              int N, const int* __restrict__ flag) {
    gemm_body(blockIdx.x, threadIdx.x, actv, W, hb, als, ald, asrcp, adstp, N, 0, flag);
}

// ---------------- fused: param canonicalization (197 blocks) | hist x4-unrolled (rest) ----------------
__global__ void k_f1(const void* W0, const void* W1, const void* W2,
                     const void* s0, const void* s1, const void* s2,
                     const void* a0, const void* a1, const void* a2,
                     const void* b0, const void* b1, const void* b2,
                     ushort_t* __restrict__ pblk, const int* __restrict__ flag,
                     const int* __restrict__ dst, int* __restrict__ cnt,
                     int* __restrict__ rank, int E) {
    if (blockIdx.x < 197) {
        int i = blockIdx.x * 256 + threadIdx.x;
        if (i >= 50304) return;
        const void* src; int off;
        if (i < 49152) {
            int seg = i / 16384; off = i % 16384;
            src = seg == 0 ? W0 : seg == 1 ? W1 : W2;
        } else if (i < 49536) {
            int j = i - 49152; int seg = j / 128; off = j % 128;
            src = seg == 0 ? s0 : seg == 1 ? s1 : s2;
        } else if (i < 49920) {
            int j = i - 49536; int seg = j / 128; off = j % 128;
            src = seg == 0 ? a0 : seg == 1 ? a1 : a2;
        } else {
            int j = i - 49920; int seg = j / 128; off = j % 128;
            src = seg == 0 ? b0 : seg == 1 ? b1 : b2;
        }
        if (flag[0]) pblk[i] = ((const ushort_t*)src)[off];
        else         pblk[i] = f2bf(((const float*)src)[off]);
    } else {
        // 4 edges per thread: independent atomic chains overlap latency
        int e0 = ((blockIdx.x - 197) * 256 + threadIdx.x) * 4;
        if (e0 + 3 < E) {
            int4 d4 = *(const int4*)(dst + e0);
            int r0 = atomicAdd(&cnt[d4.x], 1);
            int r1 = atomicAdd(&cnt[d4.y], 1);
            int r2 = atomicAdd(&cnt[d4.z], 1);
            int r3 = atomicAdd(&cnt[d4.w], 1);
            int4 r4 = {r0, r1, r2, r3};
            *(int4*)(rank + e0) = r4;
        } else {
            for (int e = e0; e < E; e++) rank[e] = atomicAdd(&cnt[dst[e]], 1);
        }
    }
}

// ---------------- fused: scan_a (nb blocks) | gemm layer-0 (rest) ----------------
__global__ __launch_bounds__(256) void k_f2(const int* __restrict__ cnt, int* __restrict__ ro,
                                            int* __restrict__ bsum, int n, int nb,
                                            const void* __restrict__ actv,
                                            const ushort_t* __restrict__ W,
                                            ushort_t* __restrict__ hb,
                                            float* __restrict__ als, float* __restrict__ ald,
                                            const ushort_t* __restrict__ asrcp,
                                            const ushort_t* __restrict__ adstp,
                                            int N, const int* __restrict__ flag) {
    if ((int)blockIdx.x < nb) {
        __shared__ int sd[256];
        int t = threadIdx.x;
        int base = blockIdx.x * 1024 + t * 4;
        int v0 = (base + 0 < n) ? cnt[base + 0] : 0;
        int v1 = (base + 1 < n) ? cnt[base + 1] : 0;
        int v2 = (base + 2 < n) ? cnt[base + 2] : 0;
        int v3 = (base + 3 < n) ? cnt[base + 3] : 0;
        int s = v0 + v1 + v2 + v3;
        sd[t] = s; __syncthreads();
        for (int off = 1; off < 256; off <<= 1) {
            int x = 0;
            if (t >= off) x = sd[t - off];
            __syncthreads();
            sd[t] += x;
            __syncthreads();
        }
        int run = sd[t] - s;
        run += v0; if (base + 0 < n) ro[base + 1] = run;
        run += v1; if (base + 1 < n) ro[base + 2] = run;
        run += v2; if (base + 2 < n) ro[base + 3] = run;
        run += v3; if (base + 3 < n) ro[base + 4] = run;
        if (t == 255) bsum[blockIdx.x] = sd[255];
    } else {
        gemm_body(blockIdx.x - nb, threadIdx.x, actv, W, hb, als, ald, asrcp, adstp, N, 1, flag);
    }
}

__global__ void k_scan_bc(int* __restrict__ ro, const int* __restrict__ bsum,
                          int n, int nb) {
    __shared__ int pre[256];
    int t = threadIdx.x;
    if (t == 0) {
        int acc = 0;
        for (int b = 0; b < nb; b++) { pre[b] = acc; acc += bsum[b]; }
    }
    __syncthreads();
    int i = blockIdx.x * 256 + t;
    if (i == 0) ro[0] = 0;
    if (i < n) ro[i + 1] += pre[i >> 10];
}

// atomic-free scatter; u16 node indices (requires N < 65536); x4 unrolled
__global__ void k_scatter(const int* __restrict__ src, const int* __restrict__ dst,
                          const int* __restrict__ ro, const int* __restrict__ rank,
                          ushort_t* __restrict__ ssrc, int E) {
    int e0 = (blockIdx.x * 256 + threadIdx.x) * 4;
    if (e0 + 3 < E) {
        int4 d4 = *(const int4*)(dst + e0);
        int4 s4 = *(const int4*)(src + e0);
        int4 r4 = *(const int4*)(rank + e0);
        ssrc[ro[d4.x] + r4.x] = (ushort_t)s4.x;
        ssrc[ro[d4.y] + r4.y] = (ushort_t)s4.y;
        ssrc[ro[d4.z] + r4.z] = (ushort_t)s4.z;
        ssrc[ro[d4.w] + r4.w] = (ushort_t)s4.w;
    } else {
        for (int e = e0; e < E; e++) ssrc[ro[dst[e]] + rank[e]] = (ushort_t)src[e];
    }
}

// ---------------- softmax + aggregation ----------------
// 4 waves / block, one NODE per wave (grid = ceil(N/4)): amortizes workgroup-slot
// occupancy limits and dispatch overhead vs 1-wave blocks (measured: 67% occupancy,
// VALUBusy 74% at 50000x 1-wave blocks).
// Per wave: single pass (softmax is shift-invariant; scores bounded, fp32-safe).
// Accumulate: 4 edges/iteration; lane = grp(edge-in-quad, lane>>4) x sub(channel
// block, lane&15); each lane loads 16B (8 bf16 channels) -> dwordx4.
// Main j-loop runs full quads without predication; single tail step handles cend%4.
__global__ __launch_bounds__(256) void k_agg(const int* __restrict__ ro,
                                             const ushort_t* __restrict__ ssrc,
                                             const ushort_t* __restrict__ hb,
                                             const float* __restrict__ als,
                                             const float* __restrict__ ald_,
                                             const ushort_t* __restrict__ bias,
                                             void* __restrict__ outp, int N, int apply_elu,
                                             int is_final, const int* __restrict__ flag) {
    int wid = threadIdx.x >> 6;
    int lane = threadIdx.x & 63;
    int n = blockIdx.x * 4 + wid;

    __shared__ __align__(16) float wsm[4][256];
    __shared__ int osm[4][64];

    if (n >= N) return;

    int r0 = ro[n], r1 = ro[n + 1];
    floatx4 ad = *(const floatx4*)(ald_ + (size_t)n * 4);
    const char* alsb = (const char*)als;
    float* wsm_ = &wsm[wid][0];
    int* osm_ = &osm[wid][0];

    int grp = lane >> 4;      // which edge within a quad of edges
    int sub = lane & 15;      // channel block: owns channels [sub*8, sub*8+8)
    int hd = sub >> 2;        // head of owned channels (8 channels never cross a head)

    float acc[8];
    #pragma unroll
    for (int k = 0; k < 8; k++) acc[k] = 0.f;
    float d0 = 0.f, d1 = 0.f, d2 = 0.f, d3 = 0.f;

    for (int base = r0; base < r1; base += 64) {
        int i = base + lane;
        if (i < r1) {
            int s = ssrc[i];
            floatx4 as = *(const floatx4*)(alsb + (s << 4));
            // leakyrelu(t) = max(t, 0.2t); w = exp(.) unshifted
            float t0 = as.x + ad.x; float w0 = __expf(fmaxf(t0, NEG_SLOPE * t0)); d0 += w0;
            float t1 = as.y + ad.y; float w1 = __expf(fmaxf(t1, NEG_SLOPE * t1)); d1 += w1;
            float t2 = as.z + ad.z; float w2 = __expf(fmaxf(t2, NEG_SLOPE * t2)); d2 += w2;
            float t3 = as.w + ad.w; float w3 = __expf(fmaxf(t3, NEG_SLOPE * t3)); d3 += w3;
            osm_[lane] = s << 8;           // row byte offset
            floatx4 w4 = {w0, w1, w2, w3};
            *(floatx4*)(wsm_ + lane * 4) = w4;
        }
        __builtin_amdgcn_wave_barrier();
        int cend = min(64, r1 - base);
        int jfull = cend & ~3;
        #pragma unroll 4
        for (int j = 0; j < jfull; j += 4) {
            int je = j + grp;
            float wj = wsm_[je * 4 + hd];
            const char* rp = (const char*)hb + (uint32)osm_[je] + (sub << 4);
            short8 hv = *(const short8*)rp;   // 8 bf16 channels, dwordx4
            #pragma unroll
            for (int k = 0; k < 8; k++) {
                union { uint32 u; float f; } c;
                c.u = ((uint32)(ushort_t)hv[k]) << 16;
                acc[k] += wj * c.f;
            }
        }
        if (jfull + grp < cend) {
            int je = jfull + grp;
            float wj = wsm_[je * 4 + hd];
            const char* rp = (const char*)hb + (uint32)osm_[je] + (sub << 4);
            short8 hv = *(const short8*)rp;
            #pragma unroll
            for (int k = 0; k < 8; k++) {
                union { uint32 u; float f; } c;
                c.u = ((uint32)(ushort_t)hv[k]) << 16;
                acc[k] += wj * c.f;
            }
        }
        __builtin_amdgcn_wave_barrier();
    }
    // fold the 4 edge-groups: lanes {sub, sub+16, sub+32, sub+48} hold the same channels
    #pragma unroll
    for (int k = 0; k < 8; k++) {
        acc[k] += __shfl_xor(acc[k], 16);
        acc[k] += __shfl_xor(acc[k], 32);
    }
    // denominators: full-wave reduce (each lane contributed its own edges)
    #pragma unroll
    for (int off = 32; off >= 1; off >>= 1) {
        d0 += __shfl_xor(d0, off); d1 += __shfl_xor(d1, off);
        d2 += __shfl_xor(d2, off); d3 += __shfl_xor(d3, off);
    }
    if (grp == 0) {
        float den = (hd == 0 ? d0 : hd == 1 ? d1 : hd == 2 ? d2 : d3) + 1e-16f;
        float inv = 1.0f / den;
        int c0 = sub << 3;
        short8 bv8 = *(const short8*)(bias + c0);
        float o[8];
        #pragma unroll
        for (int k = 0; k < 8; k++) {
            union { uint32 u; float f; } b;
            b.u = ((uint32)(ushort_t)bv8[k]) << 16;
            o[k] = acc[k] * inv + b.f;
            // ELU via exp(x)-1: |err| ~1e-7 vs expm1, below bf16 rounding
            if (apply_elu) o[k] = o[k] > 0.f ? o[k] : __expf(o[k]) - 1.f;
        }
        if (is_final && !flag[0]) {
            float* op = (float*)outp + (size_t)n * 128 + c0;
            float4 lo = {o[0], o[1], o[2], o[3]};
            float4 hi = {o[4], o[5], o[6], o[7]};
            *(float4*)op = lo;
            *(float4*)(op + 4) = hi;
        } else {
            short8 pk;
            #pragma unroll
            for (int k = 0; k < 8; k++) pk[k] = (short)f2bf(o[k]);
            *(short8*)((ushort_t*)outp + (size_t)n * 128 + c0) = pk;
        }
    }
}

extern "C" void kernel_launch(void* const* d_in, const int* in_sizes, int n_in,
                              void* d_out, int out_size, void* d_ws, size_t ws_size,
                              hipStream_t stream) {
    const void* x = d_in[0];
    const int* src = (const int*)d_in[1];
    const int* dst = (const int*)d_in[2];
    const int N = in_sizes[0] / 128;   // 50000 (< 65536 required for u16 ssrc)
    const int E = in_sizes[1];

    char* p = (char*)d_ws;
    auto alloc = [&](size_t bytes) { char* r = p; p += (bytes + 255) & ~(size_t)255; return r; };
    int*      flag  = (int*)alloc(256);
    int*      bsum  = (int*)alloc(256 * 4);
    int*      ro    = (int*)alloc((size_t)(N + 1) * 4);
    ushort_t* ssrc  = (ushort_t*)alloc((size_t)E * 2);         // also aliases cnt (int[N]) early
    ushort_t* hb    = (ushort_t*)alloc((size_t)N * 128 * 2);
    float*    als   = (float*)alloc((size_t)N * 4 * 4);
    float*    ald   = (float*)alloc((size_t)N * 4 * 4);
    ushort_t* xact  = (ushort_t*)alloc((size_t)N * 128 * 2);   // also aliases rank (int[E]) early
    ushort_t* pblk  = (ushort_t*)alloc((size_t)50304 * 2);

    int* cnt  = (int*)ssrc;    // dead once scatter overwrites ssrc
    int* rank = (int*)xact;    // dead once agg0 writes xact

    int g256e4 = (E + 1023) / 1024;
    int g256n = (N + 255) / 256;
    int nb = (N + 1023) / 1024;
    int gg = (N + 63) / 64;
    int gagg = (N + 3) / 4;

    k_sniff<<<1, 256, 0, stream>>>((const uint32*)x, flag);
    hipMemsetAsync(cnt, 0, (size_t)N * 4, stream);
    k_f1<<<197 + g256e4, 256, 0, stream>>>(
        d_in[3], d_in[7], d_in[11],
        d_in[4], d_in[8], d_in[12],
        d_in[5], d_in[9], d_in[13],
        d_in[6], d_in[10], d_in[14],
        pblk, flag, dst, cnt, rank, E);
    k_f2<<<nb + gg, 256, 0, stream>>>(cnt, ro, bsum, N, nb,
        x, pblk, hb, als, ald, pblk + 49152, pblk + 49536, N, flag);
    k_scan_bc<<<g256n, 256, 0, stream>>>(ro, bsum, N, nb);
    k_scatter<<<g256e4, 256, 0, stream>>>(src, dst, ro, rank, ssrc, E);

    for (int l = 0; l < 3; l++) {
        const ushort_t* As = pblk + 49152 + l * 128;
        const ushort_t* Ad = pblk + 49536 + l * 128;
        const ushort_t* Bc = pblk + 49920 + l * 128;
        void* outp = (l == 2) ? d_out : (void*)xact;
        if (l > 0) {
            const ushort_t* Wc = pblk + (size_t)l * 16384;
            k_gemm<<<gg, 256, 0, stream>>>(xact, Wc, hb, als, ald, As, Ad, N, flag);
        }
        k_agg<<<gagg, 256, 0, stream>>>(ro, ssrc, hb, als, ald, Bc, outp, N, l < 2 ? 1 : 0,
                                        l == 2 ? 1 : 0, flag);
    }
}

// Round 5
// 339.175 us; speedup vs baseline: 1.0334x; 1.0184x over previous
//
#include <hip/hip_runtime.h>
#include <stdint.h>

typedef unsigned short ushort_t;
typedef unsigned int uint32;

typedef __attribute__((ext_vector_type(8))) short short8;
typedef __attribute__((ext_vector_type(4))) float floatx4;
typedef __attribute__((ext_vector_type(2))) float float2v;
typedef __attribute__((ext_vector_type(4))) uint32 uint4v;

#define NEG_SLOPE 0.2f

__device__ __forceinline__ ushort_t f2bf(float f) {
    union { float f; uint32 u; } v; v.f = f;
    uint32 u = v.u;
    uint32 r = (u + 0x7fffu + ((u >> 16) & 1u)) >> 16;
    return (ushort_t)r;
}
__device__ __forceinline__ float2 bf2x(uint32 u) {
    union { uint32 u; float f; } a, b;
    a.u = u << 16; b.u = u & 0xffff0000u;
    float2 r; r.x = a.f; r.y = b.f; return r;
}

// ---------------- dtype sniffer ----------------
__global__ void k_sniff(const uint32* __restrict__ x, int* __restrict__ flag) {
    __shared__ int sh[256];
    int t = threadIdx.x;
    int c = 0;
    for (int i = t; i < 1024; i += 256) {
        uint32 h = x[i] & 0xFFFFu;
        uint32 e = (h >> 7) & 0xFFu;
        if (h == 0u || (e >= 100u && e <= 140u)) c++;
    }
    sh[t] = c; __syncthreads();
    for (int off = 128; off >= 1; off >>= 1) {
        if (t < off) sh[t] += sh[t + off];
        __syncthreads();
    }
    if (t == 0) flag[0] = (sh[0] >= 512) ? 1 : 0;
}

// ---------------- GEMM body (shared by fused layer-0 kernel and k_gemm) ----------------
__device__ __forceinline__ void gemm_body(int bid, int tid,
                                          const void* __restrict__ actv,
                                          const ushort_t* __restrict__ W,
                                          ushort_t* __restrict__ hb,
                                          float* __restrict__ als,
                                          float* __restrict__ ald,
                                          const ushort_t* __restrict__ asrcp,
                                          const ushort_t* __restrict__ adstp,
                                          int N, int layer0,
                                          const int* __restrict__ flag) {
    int wid = tid >> 6, lane = tid & 63;
    int n0 = (bid * 4 + wid) * 16;
    int mrow = lane & 15, quad = lane >> 4;
    int n = n0 + mrow;
    bool isf32 = (layer0 && !flag[0]);
    short8 a[4];
    if (n < N) {
        if (isf32) {
            const float* ar = (const float*)actv + (size_t)n * 128 + quad * 8;
            #pragma unroll
            for (int kt = 0; kt < 4; kt++) {
                float4 fa = *(const float4*)(ar + kt * 32);
                float4 fb = *(const float4*)(ar + kt * 32 + 4);
                short8 v;
                v[0] = (short)f2bf(fa.x); v[1] = (short)f2bf(fa.y);
                v[2] = (short)f2bf(fa.z); v[3] = (short)f2bf(fa.w);
                v[4] = (short)f2bf(fb.x); v[5] = (short)f2bf(fb.y);
                v[6] = (short)f2bf(fb.z); v[7] = (short)f2bf(fb.w);
                a[kt] = v;
            }
        } else {
            const ushort_t* ar = (const ushort_t*)actv + (size_t)n * 128 + quad * 8;
            #pragma unroll
            for (int kt = 0; kt < 4; kt++) a[kt] = *(const short8*)(ar + kt * 32);
        }
    } else {
        #pragma unroll
        for (int kt = 0; kt < 4; kt++) { short8 z = {0,0,0,0,0,0,0,0}; a[kt] = z; }
    }
    float ps[4], pd[4];
    #pragma unroll
    for (int t = 0; t < 8; t++) {
        if ((t & 1) == 0) {
            #pragma unroll
            for (int r = 0; r < 4; r++) { ps[r] = 0.f; pd[r] = 0.f; }
        }
        const ushort_t* wr = W + (size_t)(t * 16 + mrow) * 128 + quad * 8;
        floatx4 acc = {0.f, 0.f, 0.f, 0.f};
        #pragma unroll
        for (int kt = 0; kt < 4; kt++) {
            short8 b = *(const short8*)(wr + kt * 32);
            acc = __builtin_amdgcn_mfma_f32_16x16x32_bf16(a[kt], b, acc, 0, 0, 0);
        }
        int col = t * 16 + mrow;
        union { uint32 u; float f; } cs, cd;
        cs.u = ((uint32)asrcp[col]) << 16;
        cd.u = ((uint32)adstp[col]) << 16;
        #pragma unroll
        for (int r = 0; r < 4; r++) {
            int rn = n0 + quad * 4 + r;
            if (rn < N) hb[(size_t)rn * 128 + col] = f2bf(acc[r]);
            ps[r] += acc[r] * cs.f;
            pd[r] += acc[r] * cd.f;
        }
        if (t & 1) {
            #pragma unroll
            for (int off = 1; off <= 8; off <<= 1) {
                #pragma unroll
                for (int r = 0; r < 4; r++) {
                    ps[r] += __shfl_xor(ps[r], off);
                    pd[r] += __shfl_xor(pd[r], off);
                }
            }
            int h = t >> 1;
            if (mrow < 8) {
                int r = mrow & 3;
                float vs = r == 0 ? ps[0] : r == 1 ? ps[1] : r == 2 ? ps[2] : ps[3];
                float vd = r == 0 ? pd[0] : r == 1 ? pd[1] : r == 2 ? pd[2] : pd[3];
                int rn = n0 + quad * 4 + r;
                if (rn < N) {
                    float* dp = (mrow < 4) ? als : ald;
                    dp[(size_t)rn * 4 + h] = (mrow < 4) ? vs : vd;
                }
            }
        }
    }
}

__global__ __launch_bounds__(256) void k_gemm(const void* __restrict__ actv,
                                              const ushort_t* __restrict__ W,
                                              ushort_t* __restrict__ hb,
                                              float* __restrict__ als,
                                              float* __restrict__ ald,
                                              const ushort_t* __restrict__ asrcp,
                                              const ushort_t* __restrict__ adstp,
                                              int N, const int* __restrict__ flag) {
    gemm_body(blockIdx.x, threadIdx.x, actv, W, hb, als, ald, asrcp, adstp, N, 0, flag);
}

// ---------------- fused: param canonicalization (197 blocks) | hist x4-unrolled (rest) ----------------
__global__ void k_f1(const void* W0, const void* W1, const void* W2,
                     const void* s0, const void* s1, const void* s2,
                     const void* a0, const void* a1, const void* a2,
                     const void* b0, const void* b1, const void* b2,
                     ushort_t* __restrict__ pblk, const int* __restrict__ flag,
                     const int* __restrict__ dst, int* __restrict__ cnt,
                     int* __restrict__ rank, int E) {
    if (blockIdx.x < 197) {
        int i = blockIdx.x * 256 + threadIdx.x;
        if (i >= 50304) return;
        const void* src; int off;
        if (i < 49152) {
            int seg = i / 16384; off = i % 16384;
            src = seg == 0 ? W0 : seg == 1 ? W1 : W2;
        } else if (i < 49536) {
            int j = i - 49152; int seg = j / 128; off = j % 128;
            src = seg == 0 ? s0 : seg == 1 ? s1 : s2;
        } else if (i < 49920) {
            int j = i - 49536; int seg = j / 128; off = j % 128;
            src = seg == 0 ? a0 : seg == 1 ? a1 : a2;
        } else {
            int j = i - 49920; int seg = j / 128; off = j % 128;
            src = seg == 0 ? b0 : seg == 1 ? b1 : b2;
        }
        if (flag[0]) pblk[i] = ((const ushort_t*)src)[off];
        else         pblk[i] = f2bf(((const float*)src)[off]);
    } else {
        // 4 edges per thread: independent atomic chains overlap latency
        int e0 = ((blockIdx.x - 197) * 256 + threadIdx.x) * 4;
        if (e0 + 3 < E) {
            int4 d4 = *(const int4*)(dst + e0);
            int r0 = atomicAdd(&cnt[d4.x], 1);
            int r1 = atomicAdd(&cnt[d4.y], 1);
            int r2 = atomicAdd(&cnt[d4.z], 1);
            int r3 = atomicAdd(&cnt[d4.w], 1);
            int4 r4 = {r0, r1, r2, r3};
            *(int4*)(rank + e0) = r4;
        } else {
            for (int e = e0; e < E; e++) rank[e] = atomicAdd(&cnt[dst[e]], 1);
        }
    }
}

// ---------------- fused: scan_a (nb blocks) | gemm layer-0 (rest) ----------------
__global__ __launch_bounds__(256) void k_f2(const int* __restrict__ cnt, int* __restrict__ ro,
                                            int* __restrict__ bsum, int n, int nb,
                                            const void* __restrict__ actv,
                                            const ushort_t* __restrict__ W,
                                            ushort_t* __restrict__ hb,
                                            float* __restrict__ als, float* __restrict__ ald,
                                            const ushort_t* __restrict__ asrcp,
                                            const ushort_t* __restrict__ adstp,
                                            int N, const int* __restrict__ flag) {
    if ((int)blockIdx.x < nb) {
        __shared__ int sd[256];
        int t = threadIdx.x;
        int base = blockIdx.x * 1024 + t * 4;
        int v0 = (base + 0 < n) ? cnt[base + 0] : 0;
        int v1 = (base + 1 < n) ? cnt[base + 1] : 0;
        int v2 = (base + 2 < n) ? cnt[base + 2] : 0;
        int v3 = (base + 3 < n) ? cnt[base + 3] : 0;
        int s = v0 + v1 + v2 + v3;
        sd[t] = s; __syncthreads();
        for (int off = 1; off < 256; off <<= 1) {
            int x = 0;
            if (t >= off) x = sd[t - off];
            __syncthreads();
            sd[t] += x;
            __syncthreads();
        }
        int run = sd[t] - s;
        run += v0; if (base + 0 < n) ro[base + 1] = run;
        run += v1; if (base + 1 < n) ro[base + 2] = run;
        run += v2; if (base + 2 < n) ro[base + 3] = run;
        run += v3; if (base + 3 < n) ro[base + 4] = run;
        if (t == 255) bsum[blockIdx.x] = sd[255];
    } else {
        gemm_body(blockIdx.x - nb, threadIdx.x, actv, W, hb, als, ald, asrcp, adstp, N, 1, flag);
    }
}

__global__ void k_scan_bc(int* __restrict__ ro, const int* __restrict__ bsum,
                          int n, int nb) {
    __shared__ int pre[256];
    int t = threadIdx.x;
    if (t == 0) {
        int acc = 0;
        for (int b = 0; b < nb; b++) { pre[b] = acc; acc += bsum[b]; }
    }
    __syncthreads();
    int i = blockIdx.x * 256 + t;
    if (i == 0) ro[0] = 0;
    if (i < n) ro[i + 1] += pre[i >> 10];
}

// atomic-free scatter; u16 node indices (requires N < 65536); x4 unrolled
__global__ void k_scatter(const int* __restrict__ src, const int* __restrict__ dst,
                          const int* __restrict__ ro, const int* __restrict__ rank,
                          ushort_t* __restrict__ ssrc, int E) {
    int e0 = (blockIdx.x * 256 + threadIdx.x) * 4;
    if (e0 + 3 < E) {
        int4 d4 = *(const int4*)(dst + e0);
        int4 s4 = *(const int4*)(src + e0);
        int4 r4 = *(const int4*)(rank + e0);
        ssrc[ro[d4.x] + r4.x] = (ushort_t)s4.x;
        ssrc[ro[d4.y] + r4.y] = (ushort_t)s4.y;
        ssrc[ro[d4.z] + r4.z] = (ushort_t)s4.z;
        ssrc[ro[d4.w] + r4.w] = (ushort_t)s4.w;
    } else {
        for (int e = e0; e < E; e++) ssrc[ro[dst[e]] + rank[e]] = (ushort_t)src[e];
    }
}

// ---------------- softmax + aggregation ----------------
// 4 waves / block, one NODE per wave. Fully in-register: no LDS staging, no barriers.
// Each 16-lane group owns one edge per step (4 edges in flight per wave).
// Per step, per lane: broadcast ssrc (2B), own head's als scalar (4B, L2-resident
// 800KB table), inline w = exp(leakyrelu(als+ald)) (redundant 4x per head across the
// group - free on otherwise-idle lanes), d += w scalar, then dwordx4 of its 8 bf16
// channels and 4x float2 FMA (pk_fma). Denominator reduce: 2 shfl (was 24).
// Rationale: measured VALUBusy 74% @ 67% occupancy -> issue-bound; this cuts
// dynamic instructions/node ~260 -> ~170 and removes all barrier stalls.
__global__ __launch_bounds__(256) void k_agg(const int* __restrict__ ro,
                                             const ushort_t* __restrict__ ssrc,
                                             const ushort_t* __restrict__ hb,
                                             const float* __restrict__ als,
                                             const float* __restrict__ ald_,
                                             const ushort_t* __restrict__ bias,
                                             void* __restrict__ outp, int N, int apply_elu,
                                             int is_final, const int* __restrict__ flag) {
    int wid = threadIdx.x >> 6;
    int lane = threadIdx.x & 63;
    int n = blockIdx.x * 4 + wid;
    if (n >= N) return;

    int r0 = ro[n], r1 = ro[n + 1];
    int grp = lane >> 4;      // which edge within a quad of edges
    int sub = lane & 15;      // channel block: owns channels [sub*8, sub*8+8)
    int hd = sub >> 2;        // head of owned channels

    float adh = ald_[(size_t)n * 4 + hd];
    const char* alsb = (const char*)als;
    const char* hbb = (const char*)hb;
    int hoff = hd << 2;       // byte offset of my head's als scalar within a row
    int coff = sub << 4;      // byte offset of my 16B channel block within a row

    float2v acc2[4];
    #pragma unroll
    for (int k = 0; k < 4; k++) { float2v z = {0.f, 0.f}; acc2[k] = z; }
    float d = 0.f;

    int i = r0 + grp;
    int nfull = (r1 - r0) >> 2;
    #pragma unroll 2
    for (int t = 0; t < nfull; t++, i += 4) {
        int s = ssrc[i];
        float asv = *(const float*)(alsb + (s << 4) + hoff);
        float tv = asv + adh;
        float w = __expf(fmaxf(tv, NEG_SLOPE * tv));
        d += w;
        uint4v hv = *(const uint4v*)(hbb + (s << 8) + coff);
        #pragma unroll
        for (int k = 0; k < 4; k++) {
            float2 p = bf2x(hv[k]);
            float2v pv = {p.x, p.y};
            acc2[k] += w * pv;
        }
    }
    if (i < r1) {   // tail: groups grp < (deg & 3) take one more edge
        int s = ssrc[i];
        float asv = *(const float*)(alsb + (s << 4) + hoff);
        float tv = asv + adh;
        float w = __expf(fmaxf(tv, NEG_SLOPE * tv));
        d += w;
        uint4v hv = *(const uint4v*)(hbb + (s << 8) + coff);
        #pragma unroll
        for (int k = 0; k < 4; k++) {
            float2 p = bf2x(hv[k]);
            float2v pv = {p.x, p.y};
            acc2[k] += w * pv;
        }
    }
    // fold the 4 edge-groups: lanes {sub, sub+16, sub+32, sub+48} hold the same channels
    #pragma unroll
    for (int k = 0; k < 4; k++) {
        acc2[k].x += __shfl_xor(acc2[k].x, 16);
        acc2[k].y += __shfl_xor(acc2[k].y, 16);
        acc2[k].x += __shfl_xor(acc2[k].x, 32);
        acc2[k].y += __shfl_xor(acc2[k].y, 32);
    }
    // denominator: same fold (each lane's d covers its group's edges, own head)
    d += __shfl_xor(d, 16);
    d += __shfl_xor(d, 32);

    if (grp == 0) {
        float inv = 1.0f / (d + 1e-16f);
        int c0 = sub << 3;
        short8 bv8 = *(const short8*)(bias + c0);
        float o[8];
        #pragma unroll
        for (int k = 0; k < 4; k++) {
            union { uint32 u; float f; } blo, bhi;
            blo.u = ((uint32)(ushort_t)bv8[2 * k]) << 16;
            bhi.u = ((uint32)(ushort_t)bv8[2 * k + 1]) << 16;
            o[2 * k]     = acc2[k].x * inv + blo.f;
            o[2 * k + 1] = acc2[k].y * inv + bhi.f;
        }
        if (apply_elu) {
            #pragma unroll
            for (int k = 0; k < 8; k++)
                o[k] = o[k] > 0.f ? o[k] : __expf(o[k]) - 1.f;  // |err| below bf16 rounding
        }
        if (is_final && !flag[0]) {
            float* op = (float*)outp + (size_t)n * 128 + c0;
            float4 lo = {o[0], o[1], o[2], o[3]};
            float4 hi = {o[4], o[5], o[6], o[7]};
            *(float4*)op = lo;
            *(float4*)(op + 4) = hi;
        } else {
            short8 pk;
            #pragma unroll
            for (int k = 0; k < 8; k++) pk[k] = (short)f2bf(o[k]);
            *(short8*)((ushort_t*)outp + (size_t)n * 128 + c0) = pk;
        }
    }
}

extern "C" void kernel_launch(void* const* d_in, const int* in_sizes, int n_in,
                              void* d_out, int out_size, void* d_ws, size_t ws_size,
                              hipStream_t stream) {
    const void* x = d_in[0];
    const int* src = (const int*)d_in[1];
    const int* dst = (const int*)d_in[2];
    const int N = in_sizes[0] / 128;   // 50000 (< 65536 required for u16 ssrc)
    const int E = in_sizes[1];

    char* p = (char*)d_ws;
    auto alloc = [&](size_t bytes) { char* r = p; p += (bytes + 255) & ~(size_t)255; return r; };
    int*      flag  = (int*)alloc(256);
    int*      bsum  = (int*)alloc(256 * 4);
    int*      ro    = (int*)alloc((size_t)(N + 1) * 4);
    ushort_t* ssrc  = (ushort_t*)alloc((size_t)E * 2);         // also aliases cnt (int[N]) early
    ushort_t* hb    = (ushort_t*)alloc((size_t)N * 128 * 2);
    float*    als   = (float*)alloc((size_t)N * 4 * 4);
    float*    ald   = (float*)alloc((size_t)N * 4 * 4);
    ushort_t* xact  = (ushort_t*)alloc((size_t)N * 128 * 2);   // also aliases rank (int[E]) early
    ushort_t* pblk  = (ushort_t*)alloc((size_t)50304 * 2);

    int* cnt  = (int*)ssrc;    // dead once scatter overwrites ssrc
    int* rank = (int*)xact;    // dead once agg0 writes xact

    int g256e4 = (E + 1023) / 1024;
    int g256n = (N + 255) / 256;
    int nb = (N + 1023) / 1024;
    int gg = (N + 63) / 64;
    int gagg = (N + 3) / 4;

    k_sniff<<<1, 256, 0, stream>>>((const uint32*)x, flag);
    hipMemsetAsync(cnt, 0, (size_t)N * 4, stream);
    k_f1<<<197 + g256e4, 256, 0, stream>>>(
        d_in[3], d_in[7], d_in[11],
        d_in[4], d_in[8], d_in[12],
        d_in[5], d_in[9], d_in[13],
        d_in[6], d_in[10], d_in[14],
        pblk, flag, dst, cnt, rank, E);
    k_f2<<<nb + gg, 256, 0, stream>>>(cnt, ro, bsum, N, nb,
        x, pblk, hb, als, ald, pblk + 49152, pblk + 49536, N, flag);
    k_scan_bc<<<g256n, 256, 0, stream>>>(ro, bsum, N, nb);
    k_scatter<<<g256e4, 256, 0, stream>>>(src, dst, ro, rank, ssrc, E);

    for (int l = 0; l < 3; l++) {
        const ushort_t* As = pblk + 49152 + l * 128;
        const ushort_t* Ad = pblk + 49536 + l * 128;
        const ushort_t* Bc = pblk + 49920 + l * 128;
        void* outp = (l == 2) ? d_out : (void*)xact;
        if (l > 0) {
            const ushort_t* Wc = pblk + (size_t)l * 16384;
            k_gemm<<<gg, 256, 0, stream>>>(xact, Wc, hb, als, ald, As, Ad, N, flag);
        }
        k_agg<<<gagg, 256, 0, stream>>>(ro, ssrc, hb, als, ald, Bc, outp, N, l < 2 ? 1 : 0,
                                        l == 2 ? 1 : 0, flag);
    }
}

// Round 10
// 336.888 us; speedup vs baseline: 1.0405x; 1.0068x over previous
//
#include <hip/hip_runtime.h>
#include <stdint.h>

typedef unsigned short ushort_t;
typedef unsigned int uint32;

typedef __attribute__((ext_vector_type(8))) short short8;
typedef __attribute__((ext_vector_type(4))) float floatx4;
typedef __attribute__((ext_vector_type(2))) float float2v;
typedef __attribute__((ext_vector_type(4))) uint32 uint4v;

#define NEG_SLOPE 0.2f

__device__ __forceinline__ ushort_t f2bf(float f) {
    union { float f; uint32 u; } v; v.f = f;
    uint32 u = v.u;
    uint32 r = (u + 0x7fffu + ((u >> 16) & 1u)) >> 16;
    return (ushort_t)r;
}
__device__ __forceinline__ float2 bf2x(uint32 u) {
    union { uint32 u; float f; } a, b;
    a.u = u << 16; b.u = u & 0xffff0000u;
    float2 r; r.x = a.f; r.y = b.f; return r;
}

// ---------------- dtype sniffer (block 0) | cnt zeroing (blocks 1..nb) ----------------
__global__ void k_sniff(const uint32* __restrict__ x, int* __restrict__ flag,
                        int* __restrict__ cnt) {
    if (blockIdx.x == 0) {
        __shared__ int sh[256];
        int t = threadIdx.x;
        int c = 0;
        for (int i = t; i < 1024; i += 256) {
            uint32 h = x[i] & 0xFFFFu;
            uint32 e = (h >> 7) & 0xFFu;
            if (h == 0u || (e >= 100u && e <= 140u)) c++;
        }
        sh[t] = c; __syncthreads();
        for (int off = 128; off >= 1; off >>= 1) {
            if (t < off) sh[t] += sh[t + off];
            __syncthreads();
        }
        if (t == 0) flag[0] = (sh[0] >= 512) ? 1 : 0;
    } else {
        // zero 1024 ints per block (allocation is padded; writes past N are harmless)
        int i = ((blockIdx.x - 1) * 256 + threadIdx.x) * 4;
        int4 z = {0, 0, 0, 0};
        *(int4*)(cnt + i) = z;
    }
}

// ---------------- GEMM body (shared by fused layer-0 kernel and k_gemm) ----------------
__device__ __forceinline__ void gemm_body(int bid, int tid,
                                          const void* __restrict__ actv,
                                          const ushort_t* __restrict__ W,
                                          ushort_t* __restrict__ hb,
                                          float* __restrict__ als,
                                          float* __restrict__ ald,
                                          const ushort_t* __restrict__ asrcp,
                                          const ushort_t* __restrict__ adstp,
                                          int N, int layer0,
                                          const int* __restrict__ flag) {
    int wid = tid >> 6, lane = tid & 63;
    int n0 = (bid * 4 + wid) * 16;
    int mrow = lane & 15, quad = lane >> 4;
    int n = n0 + mrow;
    bool isf32 = (layer0 && !flag[0]);
    short8 a[4];
    if (n < N) {
        if (isf32) {
            const float* ar = (const float*)actv + (size_t)n * 128 + quad * 8;
            #pragma unroll
            for (int kt = 0; kt < 4; kt++) {
                float4 fa = *(const float4*)(ar + kt * 32);
                float4 fb = *(const float4*)(ar + kt * 32 + 4);
                short8 v;
                v[0] = (short)f2bf(fa.x); v[1] = (short)f2bf(fa.y);
                v[2] = (short)f2bf(fa.z); v[3] = (short)f2bf(fa.w);
                v[4] = (short)f2bf(fb.x); v[5] = (short)f2bf(fb.y);
                v[6] = (short)f2bf(fb.z); v[7] = (short)f2bf(fb.w);
                a[kt] = v;
            }
        } else {
            const ushort_t* ar = (const ushort_t*)actv + (size_t)n * 128 + quad * 8;
            #pragma unroll
            for (int kt = 0; kt < 4; kt++) a[kt] = *(const short8*)(ar + kt * 32);
        }
    } else {
        #pragma unroll
        for (int kt = 0; kt < 4; kt++) { short8 z = {0,0,0,0,0,0,0,0}; a[kt] = z; }
    }
    float ps[4], pd[4];
    #pragma unroll
    for (int t = 0; t < 8; t++) {
        if ((t & 1) == 0) {
            #pragma unroll
            for (int r = 0; r < 4; r++) { ps[r] = 0.f; pd[r] = 0.f; }
        }
        const ushort_t* wr = W + (size_t)(t * 16 + mrow) * 128 + quad * 8;
        floatx4 acc = {0.f, 0.f, 0.f, 0.f};
        #pragma unroll
        for (int kt = 0; kt < 4; kt++) {
            short8 b = *(const short8*)(wr + kt * 32);
            acc = __builtin_amdgcn_mfma_f32_16x16x32_bf16(a[kt], b, acc, 0, 0, 0);
        }
        int col = t * 16 + mrow;
        union { uint32 u; float f; } cs, cd;
        cs.u = ((uint32)asrcp[col]) << 16;
        cd.u = ((uint32)adstp[col]) << 16;
        #pragma unroll
        for (int r = 0; r < 4; r++) {
            int rn = n0 + quad * 4 + r;
            if (rn < N) hb[(size_t)rn * 128 + col] = f2bf(acc[r]);
            ps[r] += acc[r] * cs.f;
            pd[r] += acc[r] * cd.f;
        }
        if (t & 1) {
            #pragma unroll
            for (int off = 1; off <= 8; off <<= 1) {
                #pragma unroll
                for (int r = 0; r < 4; r++) {
                    ps[r] += __shfl_xor(ps[r], off);
                    pd[r] += __shfl_xor(pd[r], off);
                }
            }
            int h = t >> 1;
            if (mrow < 8) {
                int r = mrow & 3;
                float vs = r == 0 ? ps[0] : r == 1 ? ps[1] : r == 2 ? ps[2] : ps[3];
                float vd = r == 0 ? pd[0] : r == 1 ? pd[1] : r == 2 ? pd[2] : pd[3];
                int rn = n0 + quad * 4 + r;
                if (rn < N) {
                    float* dp = (mrow < 4) ? als : ald;
                    dp[(size_t)rn * 4 + h] = (mrow < 4) ? vs : vd;
                }
            }
        }
    }
}

__global__ __launch_bounds__(256) void k_gemm(const void* __restrict__ actv,
                                              const ushort_t* __restrict__ W,
                                              ushort_t* __restrict__ hb,
                                              float* __restrict__ als,
                                              float* __restrict__ ald,
                                              const ushort_t* __restrict__ asrcp,
                                              const ushort_t* __restrict__ adstp,
                                              int N, const int* __restrict__ flag) {
    gemm_body(blockIdx.x, threadIdx.x, actv, W, hb, als, ald, asrcp, adstp, N, 0, flag);
}

// ---------------- fused: param canonicalization (197 blocks) | hist x4-unrolled (rest) ----------------
__global__ void k_f1(const void* W0, const void* W1, const void* W2,
                     const void* s0, const void* s1, const void* s2,
                     const void* a0, const void* a1, const void* a2,
                     const void* b0, const void* b1, const void* b2,
                     ushort_t* __restrict__ pblk, const int* __restrict__ flag,
                     const int* __restrict__ dst, int* __restrict__ cnt,
                     int* __restrict__ rank, int E) {
    if (blockIdx.x < 197) {
        int i = blockIdx.x * 256 + threadIdx.x;
        if (i >= 50304) return;
        const void* src; int off;
        if (i < 49152) {
            int seg = i / 16384; off = i % 16384;
            src = seg == 0 ? W0 : seg == 1 ? W1 : W2;
        } else if (i < 49536) {
            int j = i - 49152; int seg = j / 128; off = j % 128;
            src = seg == 0 ? s0 : seg == 1 ? s1 : s2;
        } else if (i < 49920) {
            int j = i - 49536; int seg = j / 128; off = j % 128;
            src = seg == 0 ? a0 : seg == 1 ? a1 : a2;
        } else {
            int j = i - 49920; int seg = j / 128; off = j % 128;
            src = seg == 0 ? b0 : seg == 1 ? b1 : b2;
        }
        if (flag[0]) pblk[i] = ((const ushort_t*)src)[off];
        else         pblk[i] = f2bf(((const float*)src)[off]);
    } else {
        // 4 edges per thread: independent atomic chains overlap latency
        int e0 = ((blockIdx.x - 197) * 256 + threadIdx.x) * 4;
        if (e0 + 3 < E) {
            int4 d4 = *(const int4*)(dst + e0);
            int r0 = atomicAdd(&cnt[d4.x], 1);
            int r1 = atomicAdd(&cnt[d4.y], 1);
            int r2 = atomicAdd(&cnt[d4.z], 1);
            int r3 = atomicAdd(&cnt[d4.w], 1);
            int4 r4 = {r0, r1, r2, r3};
            *(int4*)(rank + e0) = r4;
        } else {
            for (int e = e0; e < E; e++) rank[e] = atomicAdd(&cnt[dst[e]], 1);
        }
    }
}

// ---------------- fused: scan_a (nb blocks) | gemm layer-0 (rest) ----------------
__global__ __launch_bounds__(256) void k_f2(const int* __restrict__ cnt, int* __restrict__ ro,
                                            int* __restrict__ bsum, int n, int nb,
                                            const void* __restrict__ actv,
                                            const ushort_t* __restrict__ W,
                                            ushort_t* __restrict__ hb,
                                            float* __restrict__ als, float* __restrict__ ald,
                                            const ushort_t* __restrict__ asrcp,
                                            const ushort_t* __restrict__ adstp,
                                            int N, const int* __restrict__ flag) {
    if ((int)blockIdx.x < nb) {
        __shared__ int sd[256];
        int t = threadIdx.x;
        int base = blockIdx.x * 1024 + t * 4;
        int v0 = (base + 0 < n) ? cnt[base + 0] : 0;
        int v1 = (base + 1 < n) ? cnt[base + 1] : 0;
        int v2 = (base + 2 < n) ? cnt[base + 2] : 0;
        int v3 = (base + 3 < n) ? cnt[base + 3] : 0;
        int s = v0 + v1 + v2 + v3;
        sd[t] = s; __syncthreads();
        for (int off = 1; off < 256; off <<= 1) {
            int x = 0;
            if (t >= off) x = sd[t - off];
            __syncthreads();
            sd[t] += x;
            __syncthreads();
        }
        int run = sd[t] - s;
        run += v0; if (base + 0 < n) ro[base + 1] = run;
        run += v1; if (base + 1 < n) ro[base + 2] = run;
        run += v2; if (base + 2 < n) ro[base + 3] = run;
        run += v3; if (base + 3 < n) ro[base + 4] = run;
        if (t == 255) bsum[blockIdx.x] = sd[255];
    } else {
        gemm_body(blockIdx.x - nb, threadIdx.x, actv, W, hb, als, ald, asrcp, adstp, N, 1, flag);
    }
}

__global__ void k_scan_bc(int* __restrict__ ro, const int* __restrict__ bsum,
                          int n, int nb) {
    __shared__ int pre[256];
    int t = threadIdx.x;
    if (t == 0) {
        int acc = 0;
        for (int b = 0; b < nb; b++) { pre[b] = acc; acc += bsum[b]; }
    }
    __syncthreads();
    int i = blockIdx.x * 256 + t;
    if (i == 0) ro[0] = 0;
    if (i < n) ro[i + 1] += pre[i >> 10];
}

// atomic-free scatter; u16 node indices (requires N < 65536); x4 unrolled
__global__ void k_scatter(const int* __restrict__ src, const int* __restrict__ dst,
                          const int* __restrict__ ro, const int* __restrict__ rank,
                          ushort_t* __restrict__ ssrc, int E) {
    int e0 = (blockIdx.x * 256 + threadIdx.x) * 4;
    if (e0 + 3 < E) {
        int4 d4 = *(const int4*)(dst + e0);
        int4 s4 = *(const int4*)(src + e0);
        int4 r4 = *(const int4*)(rank + e0);
        ssrc[ro[d4.x] + r4.x] = (ushort_t)s4.x;
        ssrc[ro[d4.y] + r4.y] = (ushort_t)s4.y;
        ssrc[ro[d4.z] + r4.z] = (ushort_t)s4.z;
        ssrc[ro[d4.w] + r4.w] = (ushort_t)s4.w;
    } else {
        for (int e = e0; e < E; e++) ssrc[ro[dst[e]] + rank[e]] = (ushort_t)src[e];
    }
}

// ---------------- softmax + aggregation ----------------
// 4 waves / block, one NODE per wave, fully in-register (no LDS, no barriers).
// The wave preloads up to 64 edge sources with ONE u16 wave-load, then each
// 16-lane group gets its edge via __shfl (1 VALU op) instead of a per-iteration
// VMEM load, breaking the ssrc->address->gather dependent-load chain.
// CORRECTNESS NOTE (R8 bug): __shfl lowers to ds_bpermute, whose source-lane
// value is only published by ACTIVE lanes. All shuffles here are executed
// unconditionally by the full wave; only edge_step is predicated. The R8
// failure (absmax 1.9e-2) was a tail __shfl inside `if (ti < cend)` reading
// from a lane that was inactive in that branch.
__global__ __launch_bounds__(256) void k_agg(const int* __restrict__ ro,
                                             const ushort_t* __restrict__ ssrc,
                                             const ushort_t* __restrict__ hb,
                                             const float* __restrict__ als,
                                             const float* __restrict__ ald_,
                                             const ushort_t* __restrict__ bias,
                                             void* __restrict__ outp, int N, int apply_elu,
                                             int is_final, const int* __restrict__ flag) {
    int wid = threadIdx.x >> 6;
    int lane = threadIdx.x & 63;
    int n = blockIdx.x * 4 + wid;
    if (n >= N) return;

    int r0 = ro[n], r1 = ro[n + 1];
    int deg = r1 - r0;
    int grp = lane >> 4;      // which edge within a quad of edges
    int sub = lane & 15;      // channel block: owns channels [sub*8, sub*8+8)
    int hd = sub >> 2;        // head of owned channels

    float adh = ald_[(size_t)n * 4 + hd];
    const char* alsb = (const char*)als;
    const char* hbb = (const char*)hb;
    int hoff = hd << 2;       // byte offset of my head's als scalar within a row
    int coff = sub << 4;      // byte offset of my 16B channel block within a row

    float2v acc2[4];
    #pragma unroll
    for (int k = 0; k < 4; k++) { float2v z = {0.f, 0.f}; acc2[k] = z; }
    float d = 0.f;

    auto edge_step = [&](int s) {
        float asv = *(const float*)(alsb + ((uint32)s << 4) + hoff);
        float tv = asv + adh;
        float w = __expf(fmaxf(tv, NEG_SLOPE * tv));
        d += w;
        uint4v hv = *(const uint4v*)(hbb + ((uint32)s << 8) + coff);
        #pragma unroll
        for (int k = 0; k < 4; k++) {
            float2 p = bf2x(hv[k]);
            float2v pv = {p.x, p.y};
            acc2[k] += w * pv;
        }
    };

    for (int base = 0; base < deg; base += 64) {
        int cend = min(deg - base, 64);
        // one coalesced wave-load covers the whole chunk's edge list
        int sv = 0;
        if (lane < cend) sv = ssrc[r0 + base + lane];
        int nfull = cend >> 2;
        #pragma unroll 4
        for (int t = 0; t < nfull; t++) {
            int s = __shfl(sv, t * 4 + grp);   // full-wave shuffle: every slot published
            edge_step(s);
        }
        int ti = nfull * 4 + grp;
        // full-wave shuffle OUTSIDE the predicate (ds_bpermute from an inactive
        // lane is undefined); &63 keeps index legal when cend==64 (tail is dead).
        int s = __shfl(sv, ti & 63);
        if (ti < cend) edge_step(s);
    }
    // fold the 4 edge-groups: lanes {sub, sub+16, sub+32, sub+48} hold the same channels
    #pragma unroll
    for (int k = 0; k < 4; k++) {
        acc2[k].x += __shfl_xor(acc2[k].x, 16);
        acc2[k].y += __shfl_xor(acc2[k].y, 16);
        acc2[k].x += __shfl_xor(acc2[k].x, 32);
        acc2[k].y += __shfl_xor(acc2[k].y, 32);
    }
    // denominator: same fold (each lane's d covers its group's edges, own head)
    d += __shfl_xor(d, 16);
    d += __shfl_xor(d, 32);

    if (grp == 0) {
        float inv = 1.0f / (d + 1e-16f);
        int c0 = sub << 3;
        short8 bv8 = *(const short8*)(bias + c0);
        float o[8];
        #pragma unroll
        for (int k = 0; k < 4; k++) {
            union { uint32 u; float f; } blo, bhi;
            blo.u = ((uint32)(ushort_t)bv8[2 * k]) << 16;
            bhi.u = ((uint32)(ushort_t)bv8[2 * k + 1]) << 16;
            o[2 * k]     = acc2[k].x * inv + blo.f;
            o[2 * k + 1] = acc2[k].y * inv + bhi.f;
        }
        if (apply_elu) {
            #pragma unroll
            for (int k = 0; k < 8; k++)
                o[k] = o[k] > 0.f ? o[k] : __expf(o[k]) - 1.f;  // |err| below bf16 rounding
        }
        if (is_final && !flag[0]) {
            float* op = (float*)outp + (size_t)n * 128 + c0;
            float4 lo = {o[0], o[1], o[2], o[3]};
            float4 hi = {o[4], o[5], o[6], o[7]};
            *(float4*)op = lo;
            *(float4*)(op + 4) = hi;
        } else {
            short8 pk;
            #pragma unroll
            for (int k = 0; k < 8; k++) pk[k] = (short)f2bf(o[k]);
            *(short8*)((ushort_t*)outp + (size_t)n * 128 + c0) = pk;
        }
    }
}

extern "C" void kernel_launch(void* const* d_in, const int* in_sizes, int n_in,
                              void* d_out, int out_size, void* d_ws, size_t ws_size,
                              hipStream_t stream) {
    const void* x = d_in[0];
    const int* src = (const int*)d_in[1];
    const int* dst = (const int*)d_in[2];
    const int N = in_sizes[0] / 128;   // 50000 (< 65536 required for u16 ssrc)
    const int E = in_sizes[1];

    char* p = (char*)d_ws;
    auto alloc = [&](size_t bytes) { char* r = p; p += (bytes + 255) & ~(size_t)255; return r; };
    int*      flag  = (int*)alloc(256);
    int*      bsum  = (int*)alloc(256 * 4);
    int*      ro    = (int*)alloc((size_t)(N + 1) * 4);
    ushort_t* ssrc  = (ushort_t*)alloc((size_t)E * 2);         // also aliases cnt (int[N]) early
    ushort_t* hb    = (ushort_t*)alloc((size_t)N * 128 * 2);
    float*    als   = (float*)alloc((size_t)N * 4 * 4);
    float*    ald   = (float*)alloc((size_t)N * 4 * 4);
    ushort_t* xact  = (ushort_t*)alloc((size_t)N * 128 * 2);   // also aliases rank (int[E]) early
    ushort_t* pblk  = (ushort_t*)alloc((size_t)50304 * 2);

    int* cnt  = (int*)ssrc;    // dead once scatter overwrites ssrc
    int* rank = (int*)xact;    // dead once agg0 writes xact

    int g256e4 = (E + 1023) / 1024;
    int g256n = (N + 255) / 256;
    int nb = (N + 1023) / 1024;
    int gg = (N + 63) / 64;
    int gagg = (N + 3) / 4;

    // block 0: dtype sniff; blocks 1..nb: zero cnt (replaces hipMemsetAsync launch)
    k_sniff<<<1 + nb, 256, 0, stream>>>((const uint32*)x, flag, cnt);
    k_f1<<<197 + g256e4, 256, 0, stream>>>(
        d_in[3], d_in[7], d_in[11],
        d_in[4], d_in[8], d_in[12],
        d_in[5], d_in[9], d_in[13],
        d_in[6], d_in[10], d_in[14],
        pblk, flag, dst, cnt, rank, E);
    k_f2<<<nb + gg, 256, 0, stream>>>(cnt, ro, bsum, N, nb,
        x, pblk, hb, als, ald, pblk + 49152, pblk + 49536, N, flag);
    k_scan_bc<<<g256n, 256, 0, stream>>>(ro, bsum, N, nb);
    k_scatter<<<g256e4, 256, 0, stream>>>(src, dst, ro, rank, ssrc, E);

    for (int l = 0; l < 3; l++) {
        const ushort_t* As = pblk + 49152 + l * 128;
        const ushort_t* Ad = pblk + 49536 + l * 128;
        const ushort_t* Bc = pblk + 49920 + l * 128;
        void* outp = (l == 2) ? d_out : (void*)xact;
        if (l > 0) {
            const ushort_t* Wc = pblk + (size_t)l * 16384;
            k_gemm<<<gg, 256, 0, stream>>>(xact, Wc, hb, als, ald, As, Ad, N, flag);
        }
        k_agg<<<gagg, 256, 0, stream>>>(ro, ssrc, hb, als, ald, Bc, outp, N, l < 2 ? 1 : 0,
                                        l == 2 ? 1 : 0, flag);
    }
}